// Round 18
// baseline (700.729 us; speedup 1.0000x reference)
//
#include <hip/hip_runtime.h>
#include <math.h>

namespace {

constexpr int B  = 2, S = 2048, NH = 16, HD = 64, HID = 1024;
constexpr int BH = B * NH;          // 32
constexpr int NSTEP2 = 8;           // 256-row scan steps

// ws layout in floats.
constexpr size_t OFF_A    = 4194304;           // [BH][S][HD] fp32
constexpr size_t OFF_Q    = 12582912;          // Qhi/Qlo bf16 pairs
constexpr size_t OFF_K    = 16777216;          // Khi/Klo bf16 pairs
constexpr size_t OFF_V    = 20971520;          // fp32 V
constexpr size_t OFF_ZI   = 25231360;          // [BH*S]
constexpr size_t OFF_PD   = 25296896;          // [BH*S]
constexpr size_t OFF_UP   = 25362432;          // [BH][7][2][128][64]
constexpr size_t WS_FLOATS = 29294592;         // ~117 MB

typedef __attribute__((ext_vector_type(8))) short bf16x8;
typedef __attribute__((ext_vector_type(4))) float f32x4;

__device__ inline unsigned short bf_rne(float x) {
  const unsigned u = __float_as_uint(x);
  return (unsigned short)((u + 0x7FFFu + ((u >> 16) & 1u)) >> 16);
}
__device__ inline float bf2f(short h) {
  return __uint_as_float((unsigned)(unsigned short)h << 16);
}
__device__ inline void split8(const float4 a, const float4 b,
                              bf16x8& hi, bf16x8& lo) {
  float v[8] = {a.x, a.y, a.z, a.w, b.x, b.y, b.z, b.w};
#pragma unroll
  for (int i = 0; i < 8; ++i) {
    const unsigned short h = bf_rne(v[i]);
    hi[i] = (short)h;
    lo[i] = (short)bf_rne(v[i] - bf2f((short)h));
  }
}
// 3-chain split-bf16 64-apply: A rows from global hi/lo, B slice from LDS ptr.
__device__ inline f32x4 apply3(const short* __restrict__ mh_,
                               const short* __restrict__ ml_,
                               const float* __restrict__ brow, int lg) {
  f32x4 o = (f32x4)0.f;
#pragma unroll
  for (int ks = 0; ks < 2; ++ks) {
    const bf16x8 mh = *(const bf16x8*)(mh_ + ks * 32 + lg * 8);
    const bf16x8 ml = *(const bf16x8*)(ml_ + ks * 32 + lg * 8);
    const float* bp = brow + ks * 32 + lg * 8;
    bf16x8 bh, bl;
    split8(*(const float4*)bp, *(const float4*)(bp + 4), bh, bl);
    o = __builtin_amdgcn_mfma_f32_16x16x32_bf16(mh, bh, o, 0, 0, 0);
    o = __builtin_amdgcn_mfma_f32_16x16x32_bf16(ml, bh, o, 0, 0, 0);
    o = __builtin_amdgcn_mfma_f32_16x16x32_bf16(mh, bl, o, 0, 0, 0);
  }
  return o;
}

// ---------------------------------------------------------------------------
// Fused pre-GEMM splits: hs -> Ahi/Alo, Wqkv -> Whi/Wlo.
// ---------------------------------------------------------------------------
__global__ __launch_bounds__(256) void split_pre(
    const float* __restrict__ hs, short* __restrict__ h1, short* __restrict__ l1,
    const float* __restrict__ wq, short* __restrict__ h2, short* __restrict__ l2) {
  const int n1 = B * S * HID / 4;
  const int n2 = 3 * HID * HID / 4;
  for (int g = blockIdx.x * 256 + threadIdx.x; g < n1 + n2; g += gridDim.x * 256) {
    const bool first = g < n1;
    const int idx = first ? g : g - n1;
    const float4 x = first ? *(const float4*)(hs + (size_t)idx * 4)
                           : *(const float4*)(wq + (size_t)idx * 4);
    short4 h, l;
    h.x = bf_rne(x.x); h.y = bf_rne(x.y); h.z = bf_rne(x.z); h.w = bf_rne(x.w);
    l.x = bf_rne(x.x - bf2f(h.x));
    l.y = bf_rne(x.y - bf2f(h.y));
    l.z = bf_rne(x.z - bf2f(h.z));
    l.w = bf_rne(x.w - bf2f(h.w));
    if (first) {
      *(short4*)(h1 + (size_t)idx * 4) = h;
      *(short4*)(l1 + (size_t)idx * 4) = l;
    } else {
      *(short4*)(h2 + (size_t)idx * 4) = h;
      *(short4*)(l2 + (size_t)idx * 4) = l;
    }
  }
}

// ---------------------------------------------------------------------------
// Fused post-scan splits: Abuf (gathered) -> A2hi/A2lo, Wd -> Wdhi/Wdlo.
// ---------------------------------------------------------------------------
__global__ __launch_bounds__(256) void split_post(
    const float* __restrict__ Abuf, short* __restrict__ h1, short* __restrict__ l1,
    const float* __restrict__ wd, short* __restrict__ h2, short* __restrict__ l2) {
  const int n1 = B * S * HID / 4;
  const int n2 = HID * HID / 4;
  for (int g = blockIdx.x * 256 + threadIdx.x; g < n1 + n2; g += gridDim.x * 256) {
    float4 x;
    if (g < n1) {
      const int m = g >> 8, q = g & 255;
      const int k0 = q * 4;
      const int b = m >> 11, s = m & (S - 1);
      const int h = k0 >> 6, d = k0 & 63;
      x = *(const float4*)(Abuf + (((size_t)(b * NH + h) * S + s) << 6) + d);
    } else {
      x = *(const float4*)(wd + (size_t)(g - n1) * 4);
    }
    short4 h, l;
    h.x = bf_rne(x.x); h.y = bf_rne(x.y); h.z = bf_rne(x.z); h.w = bf_rne(x.w);
    l.x = bf_rne(x.x - bf2f(h.x));
    l.y = bf_rne(x.y - bf2f(h.y));
    l.z = bf_rne(x.z - bf2f(h.z));
    l.w = bf_rne(x.w - bf2f(h.w));
    if (g < n1) {
      *(short4*)(h1 + (size_t)g * 4) = h;
      *(short4*)(l1 + (size_t)g * 4) = l;
    } else {
      *(short4*)(h2 + (size_t)(g - n1) * 4) = h;
      *(short4*)(l2 + (size_t)(g - n1) * 4) = l;
    }
  }
}

// ---------------------------------------------------------------------------
// Split-bf16 MFMA NT GEMM (fp32 via 3 bf16 chains), register-staged prefetch
// + XCD swizzle.  MODE 0: C = A@B^T + bias (fp32 out).
// MODE 1 (QKV): epilogue stages the fp32 tile through LDS (same-wave, no
// barrier), applies bias + RoPE (lane-local pairs) + Q-scale, splits to bf16
// and writes Qhi/Qlo/Khi/Klo + fp32 V with fully vectorized stores.
// ---------------------------------------------------------------------------
template<int MODE>
__global__ __launch_bounds__(256) void gemm_bf3(
    const short* __restrict__ Ahi, const short* __restrict__ Alo,
    const short* __restrict__ Bhi, const short* __restrict__ Blo,
    const float* __restrict__ bias, float* __restrict__ C,
    short* __restrict__ Qh, short* __restrict__ Ql,
    short* __restrict__ Kh, short* __restrict__ Kl,
    float* __restrict__ Vb, int M, int N, int K) {
  __shared__ union {
    struct {
      short ash[128][40], als[128][40], bsh[128][40], bls[128][40];
    } s;
    float stg[4][32][70];   // 35840 B fp32 staging (MODE 1 epilogue)
  } u;
  const int t = threadIdx.x;
  const int nwg = gridDim.x * gridDim.y;
  const int wg0 = blockIdx.y * gridDim.x + blockIdx.x;
  const int cpx = nwg >> 3;
  const int wg  = (wg0 & 7) * cpx + (wg0 >> 3);
  const int m0 = (wg / gridDim.x) * 128, n0 = (wg % gridDim.x) * 128;
  const int w = t >> 6, l = t & 63;
  const int wm = (w >> 1) * 64, wn = (w & 1) * 64;
  const int lr = l & 15, lk = (l >> 4) * 8;
  const int row0 = t >> 2,        c80 = (t & 3) * 8;
  const int row1 = (t + 256) >> 2, c81 = ((t + 256) & 3) * 8;

  f32x4 acc[4][4];
#pragma unroll
  for (int i = 0; i < 4; ++i)
#pragma unroll
    for (int j = 0; j < 4; ++j) acc[i][j] = (f32x4)0.f;

  uint4 rah0, rah1, ral0, ral1, rbh0, rbh1, rbl0, rbl1;
#define GLOAD(kb)                                                              \
  do {                                                                         \
    rah0 = *(const uint4*)(Ahi + (size_t)(m0 + row0) * K + (kb) + c80);        \
    rah1 = *(const uint4*)(Ahi + (size_t)(m0 + row1) * K + (kb) + c81);        \
    ral0 = *(const uint4*)(Alo + (size_t)(m0 + row0) * K + (kb) + c80);        \
    ral1 = *(const uint4*)(Alo + (size_t)(m0 + row1) * K + (kb) + c81);        \
    rbh0 = *(const uint4*)(Bhi + (size_t)(n0 + row0) * K + (kb) + c80);        \
    rbh1 = *(const uint4*)(Bhi + (size_t)(n0 + row1) * K + (kb) + c81);        \
    rbl0 = *(const uint4*)(Blo + (size_t)(n0 + row0) * K + (kb) + c80);        \
    rbl1 = *(const uint4*)(Blo + (size_t)(n0 + row1) * K + (kb) + c81);        \
  } while (0)

  GLOAD(0);
  for (int kb = 0; kb < K; kb += 32) {
    __syncthreads();
    *(uint4*)&u.s.ash[row0][c80] = rah0; *(uint4*)&u.s.ash[row1][c81] = rah1;
    *(uint4*)&u.s.als[row0][c80] = ral0; *(uint4*)&u.s.als[row1][c81] = ral1;
    *(uint4*)&u.s.bsh[row0][c80] = rbh0; *(uint4*)&u.s.bsh[row1][c81] = rbh1;
    *(uint4*)&u.s.bls[row0][c80] = rbl0; *(uint4*)&u.s.bls[row1][c81] = rbl1;
    __syncthreads();
    if (kb + 32 < K) GLOAD(kb + 32);
    bf16x8 ah[4], al[4], bh[4], bl[4];
#pragma unroll
    for (int mi = 0; mi < 4; ++mi) {
      ah[mi] = *(const bf16x8*)&u.s.ash[wm + mi * 16 + lr][lk];
      al[mi] = *(const bf16x8*)&u.s.als[wm + mi * 16 + lr][lk];
    }
#pragma unroll
    for (int ni = 0; ni < 4; ++ni) {
      bh[ni] = *(const bf16x8*)&u.s.bsh[wn + ni * 16 + lr][lk];
      bl[ni] = *(const bf16x8*)&u.s.bls[wn + ni * 16 + lr][lk];
    }
#pragma unroll
    for (int mi = 0; mi < 4; ++mi)
#pragma unroll
      for (int ni = 0; ni < 4; ++ni) {
        acc[mi][ni] = __builtin_amdgcn_mfma_f32_16x16x32_bf16(
            ah[mi], bh[ni], acc[mi][ni], 0, 0, 0);
        acc[mi][ni] = __builtin_amdgcn_mfma_f32_16x16x32_bf16(
            al[mi], bh[ni], acc[mi][ni], 0, 0, 0);
        acc[mi][ni] = __builtin_amdgcn_mfma_f32_16x16x32_bf16(
            ah[mi], bl[ni], acc[mi][ni], 0, 0, 0);
      }
  }
#undef GLOAD
  const int rq = (l >> 4) * 4;
  if (MODE == 0) {
#pragma unroll
    for (int ni = 0; ni < 4; ++ni) {
      const int col = n0 + wn + ni * 16 + lr;
      const float bv = bias[col];
#pragma unroll
      for (int mi = 0; mi < 4; ++mi)
#pragma unroll
        for (int r = 0; r < 4; ++r) {
          const int row = m0 + wm + mi * 16 + rq + r;
          C[(size_t)row * N + col] = acc[mi][ni][r] + bv;
        }
    }
  } else {
    // fused QKV epilogue v2: LDS transpose -> lane-local rows -> vector stores
    __syncthreads();   // all waves done with u.s staging
    const float PW[8] = {1.0f, 3.1622776601683795f, 10.0f, 31.622776601683793f,
                         100.0f, 316.22776601683796f, 1000.0f, 3162.2776601683795f};
    const int col0 = n0 + wn;              // wave-uniform
    const int which = col0 >> 10;          // 0 Q, 1 K, 2 V
    const int hh = (col0 >> 6) & 15;
    float bv[4];
#pragma unroll
    for (int ni = 0; ni < 4; ++ni) bv[ni] = bias[col0 + ni * 16 + lr];
    const int rrow = l & 31;               // staging-read row (0..31)
    const int ch = l >> 5;                 // col half (d 0..31 / 32..63)
#pragma unroll
    for (int pz = 0; pz < 2; ++pz) {
      // write acc pair (mi = 2pz, 2pz+1) into this wave's staging slice
#pragma unroll
      for (int mi2 = 0; mi2 < 2; ++mi2) {
        const int mi = pz * 2 + mi2;
#pragma unroll
        for (int ni = 0; ni < 4; ++ni)
#pragma unroll
          for (int r = 0; r < 4; ++r)
            u.stg[w][mi2 * 16 + rq + r][ni * 16 + lr] = acc[mi][ni][r] + bv[ni];
      }
      // same-wave LDS RAW: hardware-ordered per wave, no barrier needed
      float v[32];
#pragma unroll
      for (int k4 = 0; k4 < 8; ++k4) {
        const float4 x = *(const float4*)&u.stg[w][rrow][ch * 32 + k4 * 4];
        v[k4*4+0] = x.x; v[k4*4+1] = x.y; v[k4*4+2] = x.z; v[k4*4+3] = x.w;
      }
      const int grow = m0 + wm + pz * 32 + rrow;
      const int b = grow >> 11, sidx = grow & (S - 1);
      if (which < 2 && ch == 0) {          // rope on d = 0..15
        float nv[16];
#pragma unroll
        for (int j = 0; j < 8; ++j) {
          const float invf = 1.0f / PW[j];
          float sn, cs;
          sincosf((float)sidx * invf, &sn, &cs);
          nv[j]     = v[j] * cs - v[j + 8] * sn;
          nv[j + 8] = v[j + 8] * cs + v[j] * sn;
        }
#pragma unroll
        for (int d = 0; d < 16; ++d) v[d] = nv[d];
      }
      const size_t o = (((size_t)(b * NH + hh) * S + sidx) << 6) + ch * 32;
      if (which == 2) {
#pragma unroll
        for (int k4 = 0; k4 < 8; ++k4)
          *(float4*)(Vb + o + k4 * 4) =
              make_float4(v[k4*4], v[k4*4+1], v[k4*4+2], v[k4*4+3]);
      } else {
        if (which == 0)
#pragma unroll
          for (int i = 0; i < 32; ++i) v[i] *= 0.125f;
        short* dh = (which == 0) ? Qh : Kh;
        short* dl = (which == 0) ? Ql : Kl;
#pragma unroll
        for (int k8 = 0; k8 < 4; ++k8) {
          bf16x8 hi, lo;
          split8(make_float4(v[k8*8], v[k8*8+1], v[k8*8+2], v[k8*8+3]),
                 make_float4(v[k8*8+4], v[k8*8+5], v[k8*8+6], v[k8*8+7]),
                 hi, lo);
          *(bf16x8*)(dh + o + k8 * 8) = hi;
          *(bf16x8*)(dl + o + k8 * 8) = lo;
        }
      }
    }
  }
}

// ---------------------------------------------------------------------------
// MFMA score pass v2: Q fragments direct from global; K staged in LDS.
// ---------------------------------------------------------------------------
__global__ __launch_bounds__(256) void k3_scores(
    const short* __restrict__ Qhi, const short* __restrict__ Qlo,
    const short* __restrict__ Khi, const short* __restrict__ Klo,
    float* __restrict__ partZ, float* __restrict__ sdg) {
  const int cb = blockIdx.x, rb = blockIdx.y, bh = blockIdx.z;
  if (cb > rb) return;
  __shared__ short kh[128][72], kl[128][72];
  __shared__ float red[128][2];
  const int t = threadIdx.x;
  const int w = t >> 6, l = t & 63;
  const int wm = (w >> 1) * 64, wn = (w & 1) * 64;
  const int lr = l & 15, lg = l >> 4;
  for (int v = t; v < 1024; v += 256) {
    const int r = v >> 3, c8 = (v & 7) * 8;
    const size_t gk = (((size_t)bh * S + cb * 128 + r) << 6) + c8;
    *(uint4*)&kh[r][c8] = *(const uint4*)(Khi + gk);
    *(uint4*)&kl[r][c8] = *(const uint4*)(Klo + gk);
  }
  __syncthreads();
  f32x4 acc[4][4];
#pragma unroll
  for (int i = 0; i < 4; ++i)
#pragma unroll
    for (int j = 0; j < 4; ++j) acc[i][j] = (f32x4)0.f;
#pragma unroll
  for (int ks = 0; ks < 2; ++ks) {
    const int lk = ks * 32 + lg * 8;
    bf16x8 ah[4], al[4], bhf[4], blf[4];
#pragma unroll
    for (int mi = 0; mi < 4; ++mi) {
      const size_t qo = (((size_t)bh * S + rb * 128 + wm + mi * 16 + lr) << 6) + lk;
      ah[mi] = *(const bf16x8*)(Qhi + qo);
      al[mi] = *(const bf16x8*)(Qlo + qo);
    }
#pragma unroll
    for (int ni = 0; ni < 4; ++ni) {
      bhf[ni] = *(const bf16x8*)&kh[wn + ni * 16 + lr][lk];
      blf[ni] = *(const bf16x8*)&kl[wn + ni * 16 + lr][lk];
    }
#pragma unroll
    for (int mi = 0; mi < 4; ++mi)
#pragma unroll
      for (int ni = 0; ni < 4; ++ni) {
        acc[mi][ni] = __builtin_amdgcn_mfma_f32_16x16x32_bf16(
            ah[mi], bhf[ni], acc[mi][ni], 0, 0, 0);
        acc[mi][ni] = __builtin_amdgcn_mfma_f32_16x16x32_bf16(
            al[mi], bhf[ni], acc[mi][ni], 0, 0, 0);
        acc[mi][ni] = __builtin_amdgcn_mfma_f32_16x16x32_bf16(
            ah[mi], blf[ni], acc[mi][ni], 0, 0, 0);
      }
  }
  const int rq = lg * 4;
  const int rowbase = rb * 128 + wm, colbase = cb * 128 + wn;
  float rp[4][4];
#pragma unroll
  for (int mi = 0; mi < 4; ++mi)
#pragma unroll
    for (int r = 0; r < 4; ++r) rp[mi][r] = 0.f;
#pragma unroll
  for (int mi = 0; mi < 4; ++mi)
#pragma unroll
    for (int ni = 0; ni < 4; ++ni)
#pragma unroll
      for (int r = 0; r < 4; ++r) {
        const int rG = rowbase + mi * 16 + rq + r;
        const int cG = colbase + ni * 16 + lr;
        if (cG <= rG) rp[mi][r] += __expf(acc[mi][ni][r]);
        if (cG == rG) sdg[(size_t)bh * S + rG] = acc[mi][ni][r];
      }
#pragma unroll
  for (int off = 1; off < 16; off <<= 1)
#pragma unroll
    for (int mi = 0; mi < 4; ++mi)
#pragma unroll
      for (int r = 0; r < 4; ++r)
        rp[mi][r] += __shfl_xor(rp[mi][r], off, 64);
  if (lr == 0)
#pragma unroll
    for (int mi = 0; mi < 4; ++mi)
#pragma unroll
      for (int r = 0; r < 4; ++r)
        red[wm + mi * 16 + rq + r][w & 1] = rp[mi][r];
  __syncthreads();
  if (t < 128)
    partZ[(((size_t)bh * 16 + rb) * 16 + cb) * 128 + t] = red[t][0] + red[t][1];
}

// ---------------------------------------------------------------------------
__global__ __launch_bounds__(256) void k3_reduce(
    const float* __restrict__ partZ, float* __restrict__ zinv,
    float* __restrict__ pdg) {
  const int R = blockIdx.x * 256 + threadIdx.x;
  const int bh = R >> 11, r = R & 2047;
  const int rb = r >> 7, row = r & 127;
  float Z = 0.f;
  for (int c = 0; c <= rb; ++c)
    Z += partZ[(((size_t)bh*16 + rb)*16 + c)*128 + row];
  const float zi = 1.f / Z;
  zinv[R] = zi;
  pdg[R] = __expf(pdg[R]) * zi;
}

// ---------------------------------------------------------------------------
// Per-64-block unit-lower-triangular inverse of (I - N), 256 threads.
// ---------------------------------------------------------------------------
__global__ __launch_bounds__(256) void k4_minv(
    const short* __restrict__ Qhi, const short* __restrict__ Qlo,
    const short* __restrict__ Khi, const short* __restrict__ Klo,
    const float* __restrict__ zinv, short* __restrict__ Mrh,
    short* __restrict__ Mrl, short* __restrict__ P10h,
    short* __restrict__ P10l) {
  const int bh = blockIdx.y, ib = blockIdx.x;
  const int r0 = ib * 64;
  __shared__ float Nb[64][68];
  __shared__ float X[64][68];
  const int t = threadIdx.x;
  const int w = t >> 6, l = t & 63;
  const int lr = l & 15, lg = l >> 4;

  bf16x8 qfh[2], qfl[2];
  const size_t qbase = (((size_t)bh * S + r0 + 16 * w + lr) << 6);
#pragma unroll
  for (int ks = 0; ks < 2; ++ks) {
    qfh[ks] = *(const bf16x8*)(Qhi + qbase + ks * 32 + lg * 8);
    qfl[ks] = *(const bf16x8*)(Qlo + qbase + ks * 32 + lg * 8);
  }
  const int rloc0 = 16 * w + lg * 4;
  float ziv[4];
#pragma unroll
  for (int i = 0; i < 4; ++i) ziv[i] = zinv[(size_t)bh * S + r0 + rloc0 + i];

  {
    f32x4 acc[4];
#pragma unroll
    for (int i = 0; i < 4; ++i) acc[i] = (f32x4)0.f;
    const size_t kbase = ((size_t)bh * S + r0) << 6;
#pragma unroll
    for (int ks = 0; ks < 2; ++ks) {
#pragma unroll
      for (int ni = 0; ni < 4; ++ni) {
        const size_t kb = kbase + (((size_t)(16 * ni + lr)) << 6) + ks * 32 + lg * 8;
        const bf16x8 bhf = *(const bf16x8*)(Khi + kb);
        const bf16x8 blf = *(const bf16x8*)(Klo + kb);
        acc[ni] = __builtin_amdgcn_mfma_f32_16x16x32_bf16(qfh[ks], bhf, acc[ni], 0, 0, 0);
        acc[ni] = __builtin_amdgcn_mfma_f32_16x16x32_bf16(qfl[ks], bhf, acc[ni], 0, 0, 0);
        acc[ni] = __builtin_amdgcn_mfma_f32_16x16x32_bf16(qfh[ks], blf, acc[ni], 0, 0, 0);
      }
    }
#pragma unroll
    for (int ni = 0; ni < 4; ++ni) {
      const int c = 16 * ni + lr;
#pragma unroll
      for (int i = 0; i < 4; ++i) {
        const int r = rloc0 + i;
        Nb[r][c] = (c < r) ? __expf(acc[ni][i]) * ziv[i] : 0.f;
      }
    }
  }
  if (ib & 1) {
    f32x4 p[4];
#pragma unroll
    for (int i = 0; i < 4; ++i) p[i] = (f32x4)0.f;
    const size_t kbase = ((size_t)bh * S + r0 - 64) << 6;
#pragma unroll
    for (int ks = 0; ks < 2; ++ks) {
#pragma unroll
      for (int ni = 0; ni < 4; ++ni) {
        const size_t kb = kbase + (((size_t)(16 * ni + lr)) << 6) + ks * 32 + lg * 8;
        const bf16x8 bhf = *(const bf16x8*)(Khi + kb);
        const bf16x8 blf = *(const bf16x8*)(Klo + kb);
        p[ni] = __builtin_amdgcn_mfma_f32_16x16x32_bf16(qfh[ks], bhf, p[ni], 0, 0, 0);
        p[ni] = __builtin_amdgcn_mfma_f32_16x16x32_bf16(qfl[ks], bhf, p[ni], 0, 0, 0);
        p[ni] = __builtin_amdgcn_mfma_f32_16x16x32_bf16(qfh[ks], blf, p[ni], 0, 0, 0);
      }
    }
    const size_t pbase = (((size_t)bh * 16 + (ib >> 1)) * 64) * 64;
#pragma unroll
    for (int ni = 0; ni < 4; ++ni) {
      const int c = 16 * ni + lr;
#pragma unroll
      for (int i = 0; i < 4; ++i) {
        const float val = __expf(p[ni][i]) * ziv[i];
        const unsigned short h = bf_rne(val);
        P10h[pbase + (size_t)(rloc0 + i) * 64 + c] = (short)h;
        P10l[pbase + (size_t)(rloc0 + i) * 64 + c] = (short)bf_rne(val - bf2f((short)h));
      }
    }
  }
  {
    const int c = t & 63, g = t >> 6;
#pragma unroll
    for (int i = 0; i < 16; ++i) {
      const int r = 16 * g + i;
      X[r][c] = (r == c) ? 1.f : 0.f;
    }
  }
  __syncthreads();

  const int c = t & 63, g = t >> 6;
  if (w == 0) {
    for (int rr = 1; rr < 16; ++rr) {
      float a = 0.f;
      for (int j = 0; j < rr; ++j) a += Nb[rr][j] * X[j][l];
      X[rr][l] += a;
    }
  }
  __syncthreads();
#pragma unroll
  for (int I = 1; I < 4; ++I) {
    {
      const int rb4 = 16 * I + 4 * g;
      float s0 = 0.f, s1 = 0.f, s2 = 0.f, s3 = 0.f;
      for (int j = 0; j < 16 * I; j += 4) {
        const float4 n0 = *(const float4*)&Nb[rb4 + 0][j];
        const float4 n1 = *(const float4*)&Nb[rb4 + 1][j];
        const float4 n2 = *(const float4*)&Nb[rb4 + 2][j];
        const float4 n3 = *(const float4*)&Nb[rb4 + 3][j];
        const float x0 = X[j + 0][c], x1 = X[j + 1][c];
        const float x2 = X[j + 2][c], x3 = X[j + 3][c];
        s0 += n0.x * x0 + n0.y * x1 + n0.z * x2 + n0.w * x3;
        s1 += n1.x * x0 + n1.y * x1 + n1.z * x2 + n1.w * x3;
        s2 += n2.x * x0 + n2.y * x1 + n2.z * x2 + n2.w * x3;
        s3 += n3.x * x0 + n3.y * x1 + n3.z * x2 + n3.w * x3;
      }
      X[rb4 + 0][c] += s0; X[rb4 + 1][c] += s1;
      X[rb4 + 2][c] += s2; X[rb4 + 3][c] += s3;
    }
    __syncthreads();
    if (w == 0) {
      const int rb = 16 * I;
      for (int rr = 1; rr < 16; ++rr) {
        const int r = rb + rr;
        float a = 0.f;
        for (int j = rb; j < r; ++j) a += Nb[r][j] * X[j][l];
        X[r][l] += a;
      }
    }
    __syncthreads();
  }

  const size_t mb = (((size_t)bh * 32 + ib) * 64) * 64;
  for (int v = t; v < 4096; v += 256) {
    const int r = v >> 6, cc = v & 63;
    const float x = X[r][cc];
    const unsigned short h = bf_rne(x);
    Mrh[mb + v] = (short)h;
    Mrl[mb + v] = (short)bf_rne(x - bf2f((short)h));
  }
}

// ---------------------------------------------------------------------------
// Scan step s (256 rows) off-diagonal accumulate, FULL MFMA, XCD-paired grid.
// ---------------------------------------------------------------------------
__global__ __launch_bounds__(256) void k5_acc(
    const short* __restrict__ Qhi, const short* __restrict__ Qlo,
    const short* __restrict__ Khi, const short* __restrict__ Klo,
    const float* __restrict__ Abuf, const float* __restrict__ zinv,
    float* __restrict__ up, int s) {
  __shared__ float Es[128][68];
  __shared__ float Ats[64][68];
  const int x = blockIdx.x;
  const int ng = gridDim.x >> 6;           // /(2*BH)
  const int p = ((x >> 4) << 3) + (x & 7); // pair index
  const int rh = (x >> 3) & 1;
  const int g = p % ng;
  const int bh = p / ng;
  const int t = threadIdx.x;
  const int w = t >> 6, l = t & 63;
  const int lr = l & 15, lg = l >> 4;
  const int rw = 32 * w;
  const int base = s * 256 + rh * 128;

  bf16x8 qfh[2][2], qfl[2][2];
#pragma unroll
  for (int mi = 0; mi < 2; ++mi)
#pragma unroll
    for (int ks = 0; ks < 2; ++ks) {
      const size_t qo = (((size_t)bh * S + base + rw + mi * 16 + lr) << 6) + ks * 32 + lg * 8;
      qfh[mi][ks] = *(const bf16x8*)(Qhi + qo);
      qfl[mi][ks] = *(const bf16x8*)(Qlo + qo);
    }
  float ziv[2][4];
#pragma unroll
  for (int mi = 0; mi < 2; ++mi)
#pragma unroll
    for (int r = 0; r < 4; ++r)
      ziv[mi][r] = zinv[(size_t)bh * S + base + rw + mi * 16 + lg * 4 + r];

  f32x4 out[2][4];
#pragma unroll
  for (int mi = 0; mi < 2; ++mi)
#pragma unroll
    for (int ni = 0; ni < 4; ++ni) out[mi][ni] = (f32x4)0.f;

  for (int j = g; j < 2 * s; j += ng) {
    for (int h = 0; h < 2; ++h) {
      __syncthreads();
      for (int v = t; v < 1024; v += 256) {
        const int d = v & 63, sq = v >> 6;
        const size_t ab = ((size_t)bh * S + j * 128 + h * 64 + sq * 4) << 6;
        float4 o;
        o.x = Abuf[ab + d];
        o.y = Abuf[ab + 64 + d];
        o.z = Abuf[ab + 128 + d];
        o.w = Abuf[ab + 192 + d];
        *(float4*)&Ats[d][sq * 4] = o;
      }
      f32x4 qk[2][4];
#pragma unroll
      for (int mi = 0; mi < 2; ++mi)
#pragma unroll
        for (int ni = 0; ni < 4; ++ni) qk[mi][ni] = (f32x4)0.f;
#pragma unroll
      for (int ks = 0; ks < 2; ++ks) {
#pragma unroll
        for (int ni = 0; ni < 4; ++ni) {
          const size_t ko = (((size_t)bh * S + j * 128 + h * 64 + ni * 16 + lr) << 6) + ks * 32 + lg * 8;
          const bf16x8 kh8 = *(const bf16x8*)(Khi + ko);
          const bf16x8 kl8 = *(const bf16x8*)(Klo + ko);
#pragma unroll
          for (int mi = 0; mi < 2; ++mi) {
            qk[mi][ni] = __builtin_amdgcn_mfma_f32_16x16x32_bf16(
                qfh[mi][ks], kh8, qk[mi][ni], 0, 0, 0);
            qk[mi][ni] = __builtin_amdgcn_mfma_f32_16x16x32_bf16(
                qfl[mi][ks], kh8, qk[mi][ni], 0, 0, 0);
            qk[mi][ni] = __builtin_amdgcn_mfma_f32_16x16x32_bf16(
                qfh[mi][ks], kl8, qk[mi][ni], 0, 0, 0);
          }
        }
      }
#pragma unroll
      for (int mi = 0; mi < 2; ++mi)
#pragma unroll
        for (int ni = 0; ni < 4; ++ni)
#pragma unroll
          for (int r = 0; r < 4; ++r)
            Es[rw + mi * 16 + lg * 4 + r][ni * 16 + lr] =
                __expf(qk[mi][ni][r]) * ziv[mi][r];
      __syncthreads();
#pragma unroll
      for (int ks = 0; ks < 2; ++ks) {
        bf16x8 eh[2], el[2];
#pragma unroll
        for (int mi = 0; mi < 2; ++mi) {
          const float* ep = &Es[rw + mi * 16 + lr][ks * 32 + lg * 8];
          split8(*(const float4*)ep, *(const float4*)(ep + 4), eh[mi], el[mi]);
        }
#pragma unroll
        for (int ni = 0; ni < 4; ++ni) {
          const float* ap = &Ats[ni * 16 + lr][ks * 32 + lg * 8];
          bf16x8 ah8, al8;
          split8(*(const float4*)ap, *(const float4*)(ap + 4), ah8, al8);
#pragma unroll
          for (int mi = 0; mi < 2; ++mi) {
            out[mi][ni] = __builtin_amdgcn_mfma_f32_16x16x32_bf16(
                eh[mi], ah8, out[mi][ni], 0, 0, 0);
            out[mi][ni] = __builtin_amdgcn_mfma_f32_16x16x32_bf16(
                el[mi], ah8, out[mi][ni], 0, 0, 0);
            out[mi][ni] = __builtin_amdgcn_mfma_f32_16x16x32_bf16(
                eh[mi], al8, out[mi][ni], 0, 0, 0);
          }
        }
      }
    }
  }
  float* ub = up + (((size_t)(bh * 7 + g) * 2 + rh) << 13);
#pragma unroll
  for (int mi = 0; mi < 2; ++mi)
#pragma unroll
    for (int ni = 0; ni < 4; ++ni)
#pragma unroll
      for (int r = 0; r < 4; ++r)
        ub[(size_t)(rw + mi * 16 + lg * 4 + r) * 64 + ni * 16 + lr] =
            out[mi][ni][r];
}

// ---------------------------------------------------------------------------
// Scan step s finalize (256 rows), grid (4, BH), d-quads of 16.
// ---------------------------------------------------------------------------
__global__ __launch_bounds__(256) void k5_fin(
    const short* __restrict__ Qhi, const short* __restrict__ Qlo,
    const short* __restrict__ Khi, const short* __restrict__ Klo,
    const float* __restrict__ V, const float* __restrict__ pd,
    const float* __restrict__ zinv, const float* __restrict__ up,
    const short* __restrict__ Mrh, const short* __restrict__ Mrl,
    const short* __restrict__ P10h, const short* __restrict__ P10l,
    float* __restrict__ Abuf, int s) {
  const int d0 = blockIdx.x * 16;
  const int bh = blockIdx.y;
  const int t = threadIdx.x;
  const int w = t >> 6, l = t & 63;
  const int lr = l & 15, lg = l >> 4;
  const int base = s * 256;
  __shared__ float uT[16][260];
  __shared__ float aT[16][132];
  __shared__ float Es[128][68];
  const int ng = (2 * s < 7) ? 2 * s : 7;

  for (int v = t; v < 1024; v += 256) {
    const int r = v >> 2, f = v & 3;
    const int R = base + r;
    const float4 x = *(const float4*)(V + (((size_t)bh * S + R) << 6) + d0 + f * 4);
    const float p = pd[(size_t)bh * S + R];
    float a0 = p * x.x, a1 = p * x.y, a2 = p * x.z, a3 = p * x.w;
    const int rh = r >> 7, rr = r & 127;
    for (int g = 0; g < ng; ++g) {
      const float4 y = *(const float4*)(
          up + (((size_t)(bh * 7 + g) * 2 + rh) << 13) + (rr << 6) + d0 + f * 4);
      a0 += y.x; a1 += y.y; a2 += y.z; a3 += y.w;
    }
    uT[f * 4 + 0][r] = a0; uT[f * 4 + 1][r] = a1;
    uT[f * 4 + 2][r] = a2; uT[f * 4 + 3][r] = a3;
  }
  __syncthreads();
  const size_t mstep = (size_t)bh * 32 + s * 4;
  {
    const size_t mb = ((mstep + 0) * 64 + 16 * w + lr) * 64;
    const f32x4 o = apply3(Mrh + mb, Mrl + mb, &uT[lr][0], lg);
#pragma unroll
    for (int i = 0; i < 4; ++i) {
      const int r = 16 * w + lg * 4 + i;
      Abuf[(((size_t)bh * S + base + r) << 6) + d0 + lr] = o[i];
      aT[lr][r] = o[i];
    }
  }
  __syncthreads();
  {
    const size_t pb = (((size_t)bh * 16 + 2 * s) * 64 + 16 * w + lr) * 64;
    const f32x4 o = apply3(P10h + pb, P10l + pb, &aT[lr][0], lg);
#pragma unroll
    for (int i = 0; i < 4; ++i)
      uT[lr][64 + 16 * w + lg * 4 + i] += o[i];
  }
  __syncthreads();
  {
    const size_t mb = ((mstep + 1) * 64 + 16 * w + lr) * 64;
    const f32x4 o = apply3(Mrh + mb, Mrl + mb, &uT[lr][64], lg);
#pragma unroll
    for (int i = 0; i < 4; ++i) {
      const int r = 16 * w + lg * 4 + i;
      Abuf[(((size_t)bh * S + base + 64 + r) << 6) + d0 + lr] = o[i];
      aT[lr][64 + r] = o[i];
    }
  }
  {
    const int rw = 32 * w;
    bf16x8 qh_[2][2], ql_[2][2];
#pragma unroll
    for (int mi = 0; mi < 2; ++mi)
#pragma unroll
      for (int ks = 0; ks < 2; ++ks) {
        const size_t qo = (((size_t)bh * S + base + 128 + rw + mi * 16 + lr) << 6) + ks * 32 + lg * 8;
        qh_[mi][ks] = *(const bf16x8*)(Qhi + qo);
        ql_[mi][ks] = *(const bf16x8*)(Qlo + qo);
      }
    float zv[2][4];
#pragma unroll
    for (int mi = 0; mi < 2; ++mi)
#pragma unroll
      for (int i = 0; i < 4; ++i)
        zv[mi][i] = zinv[(size_t)bh * S + base + 128 + rw + mi * 16 + lg * 4 + i];
    for (int ch = 0; ch < 2; ++ch) {
      __syncthreads();
      f32x4 qk[2][4];
#pragma unroll
      for (int mi = 0; mi < 2; ++mi)
#pragma unroll
        for (int ni = 0; ni < 4; ++ni) qk[mi][ni] = (f32x4)0.f;
#pragma unroll
      for (int ks = 0; ks < 2; ++ks) {
#pragma unroll
        for (int ni = 0; ni < 4; ++ni) {
          const size_t ko = (((size_t)bh * S + base + ch * 64 + ni * 16 + lr) << 6) + ks * 32 + lg * 8;
          const bf16x8 kh8 = *(const bf16x8*)(Khi + ko);
          const bf16x8 kl8 = *(const bf16x8*)(Klo + ko);
#pragma unroll
          for (int mi = 0; mi < 2; ++mi) {
            qk[mi][ni] = __builtin_amdgcn_mfma_f32_16x16x32_bf16(
                qh_[mi][ks], kh8, qk[mi][ni], 0, 0, 0);
            qk[mi][ni] = __builtin_amdgcn_mfma_f32_16x16x32_bf16(
                ql_[mi][ks], kh8, qk[mi][ni], 0, 0, 0);
            qk[mi][ni] = __builtin_amdgcn_mfma_f32_16x16x32_bf16(
                qh_[mi][ks], kl8, qk[mi][ni], 0, 0, 0);
          }
        }
      }
#pragma unroll
      for (int mi = 0; mi < 2; ++mi)
#pragma unroll
        for (int ni = 0; ni < 4; ++ni)
#pragma unroll
          for (int i = 0; i < 4; ++i)
            Es[rw + mi * 16 + lg * 4 + i][ni * 16 + lr] =
                __expf(qk[mi][ni][i]) * zv[mi][i];
      __syncthreads();
#pragma unroll
      for (int mi = 0; mi < 2; ++mi) {
        f32x4 o = (f32x4)0.f;
#pragma unroll
        for (int kq = 0; kq < 2; ++kq) {
          const float* ep = &Es[rw + mi * 16 + lr][kq * 32 + lg * 8];
          bf16x8 eh, el;
          split8(*(const float4*)ep, *(const float4*)(ep + 4), eh, el);
          const float* ap = &aT[lr][ch * 64 + kq * 32 + lg * 8];
          bf16x8 ah, al;
          split8(*(const float4*)ap, *(const float4*)(ap + 4), ah, al);
          o = __builtin_amdgcn_mfma_f32_16x16x32_bf16(eh, ah, o, 0, 0, 0);
          o = __builtin_amdgcn_mfma_f32_16x16x32_bf16(el, ah, o, 0, 0, 0);
          o = __builtin_amdgcn_mfma_f32_16x16x32_bf16(eh, al, o, 0, 0, 0);
        }
#pragma unroll
        for (int i = 0; i < 4; ++i)
          uT[lr][128 + rw + mi * 16 + lg * 4 + i] += o[i];
      }
    }
  }
  __syncthreads();
  {
    const size_t mb = ((mstep + 2) * 64 + 16 * w + lr) * 64;
    const f32x4 o = apply3(Mrh + mb, Mrl + mb, &uT[lr][128], lg);
#pragma unroll
    for (int i = 0; i < 4; ++i) {
      const int r = 16 * w + lg * 4 + i;
      Abuf[(((size_t)bh * S + base + 128 + r) << 6) + d0 + lr] = o[i];
      aT[lr][r] = o[i];
    }
  }
  __syncthreads();
  {
    const size_t pb = (((size_t)bh * 16 + 2 * s + 1) * 64 + 16 * w + lr) * 64;
    const f32x4 o = apply3(P10h + pb, P10l + pb, &aT[lr][0], lg);
#pragma unroll
    for (int i = 0; i < 4; ++i)
      uT[lr][192 + 16 * w + lg * 4 + i] += o[i];
  }
  __syncthreads();
  {
    const size_t mb = ((mstep + 3) * 64 + 16 * w + lr) * 64;
    const f32x4 o = apply3(Mrh + mb, Mrl + mb, &uT[lr][192], lg);
#pragma unroll
    for (int i = 0; i < 4; ++i) {
      const int r = 16 * w + lg * 4 + i;
      Abuf[(((size_t)bh * S + base + 192 + r) << 6) + d0 + lr] = o[i];
    }
  }
}

} // namespace

extern "C" void kernel_launch(void* const* d_in, const int* in_sizes, int n_in,
                              void* d_out, int out_size, void* d_ws, size_t ws_size,
                              hipStream_t stream) {
  const float* hs   = (const float*)d_in[0];
  const float* Wqkv = (const float*)d_in[1];
  const float* bqkv = (const float*)d_in[2];
  const float* Wd   = (const float*)d_in[3];
  const float* bd   = (const float*)d_in[4];
  float* out = (float*)d_out;
  float* W   = (float*)d_ws;
  if (ws_size < WS_FLOATS * sizeof(float)) return;  // insufficient scratch

  float* partZ = W;               // transient (scores->reduce)
  float* Abuf  = W + OFF_A;
  short* Qhi   = (short*)(W + OFF_Q);
  short* Qlo   = Qhi + 4194304;
  short* Khi   = (short*)(W + OFF_K);
  short* Klo   = Khi + 4194304;
  float* Vb    = W + OFF_V;
  float* zi    = W + OFF_ZI;
  float* pdg   = W + OFF_PD;
  float* up    = W + OFF_UP;

  char* wsb = (char*)d_ws;
  short* Ahi  = (short*)(wsb);                 // 0..8.4MB
  short* Alo  = Ahi + 4194304;                 // 8.4..16.8MB
  short* Whi  = (short*)(wsb + 16777216);      // 16.8..23.1MB
  short* Wlo  = Whi + 3145728;                 // 23.1..29.4MB
  short* A2hi = (short*)(wsb + 50331648);      // post-scan: Q region (dead)
  short* A2lo = A2hi + 4194304;
  short* Wdhi = (short*)(wsb + 67108864);      // post-scan: K region (dead)
  short* Wdlo = Wdhi + 1048576;
  short* P10h = (short*)(wsb);                 // 0..4.2MB (split ops dead)
  short* P10l = P10h + 2097152;                // 4.2..8.4MB
  short* Mrh  = (short*)(wsb + 33554432);      // 33.5..41.9MB
  short* Mrl  = Mrh + 4194304;                 // 41.9..50.3MB

  split_pre<<<dim3(2048), 256, 0, stream>>>(hs, Ahi, Alo, Wqkv, Whi, Wlo);
  gemm_bf3<1><<<dim3(24, 32), 256, 0, stream>>>(Ahi, Alo, Whi, Wlo, bqkv,
                                                nullptr, Qhi, Qlo, Khi, Klo,
                                                Vb, B*S, 3*HID, HID);
  k3_scores<<<dim3(16, 16, BH), 256, 0, stream>>>(Qhi, Qlo, Khi, Klo, partZ, pdg);
  k3_reduce<<<dim3(BH * S / 256), 256, 0, stream>>>(partZ, zi, pdg);
  k4_minv<<<dim3(S / 64, BH), 256, 0, stream>>>(Qhi, Qlo, Khi, Klo, zi,
                                                Mrh, Mrl, P10h, P10l);
  for (int s = 0; s < NSTEP2; ++s) {
    if (s > 0) {
      const int ng = (2 * s < 7) ? 2 * s : 7;
      k5_acc<<<dim3(ng * 2 * BH), 256, 0, stream>>>(Qhi, Qlo, Khi, Klo, Abuf,
                                                    zi, up, s);
    }
    k5_fin<<<dim3(4, BH), 256, 0, stream>>>(Qhi, Qlo, Khi, Klo, Vb, pdg, zi, up,
                                            Mrh, Mrl, P10h, P10l, Abuf, s);
  }
  split_post<<<dim3(2048), 256, 0, stream>>>(Abuf, A2hi, A2lo, Wd, Wdhi, Wdlo);
  gemm_bf3<0><<<dim3(8, 32), 256, 0, stream>>>(A2hi, A2lo, Wdhi, Wdlo, bd, out,
                                               nullptr, nullptr, nullptr,
                                               nullptr, nullptr, B*S, HID, HID);
}

// Round 19
// 641.550 us; speedup vs baseline: 1.0922x; 1.0922x over previous
//
#include <hip/hip_runtime.h>
#include <math.h>

namespace {

constexpr int B  = 2, S = 2048, NH = 16, HD = 64, HID = 1024;
constexpr int BH = B * NH;          // 32
constexpr int NSTEP2 = 8;           // 256-row scan steps

// ws layout in floats.
constexpr size_t OFF_A    = 4194304;           // [BH][S][HD] fp32
constexpr size_t OFF_Q    = 12582912;          // Qc combined hi|lo bf16 (16MB)
constexpr size_t OFF_K    = 16777216;          // Kc combined hi|lo bf16 (16MB)
constexpr size_t OFF_V    = 20971520;          // fp32 V
constexpr size_t OFF_ZI   = 25231360;          // [BH*S]
constexpr size_t OFF_PD   = 25296896;          // [BH*S]
constexpr size_t OFF_UP   = 25362432;          // [BH][7][2][128][64]
constexpr size_t WS_FLOATS = 29294592;         // ~117 MB

typedef __attribute__((ext_vector_type(8))) short bf16x8;
typedef __attribute__((ext_vector_type(4))) float f32x4;

__device__ inline unsigned short bf_rne(float x) {
  const unsigned u = __float_as_uint(x);
  return (unsigned short)((u + 0x7FFFu + ((u >> 16) & 1u)) >> 16);
}
__device__ inline float bf2f(short h) {
  return __uint_as_float((unsigned)(unsigned short)h << 16);
}
__device__ inline void split8(const float4 a, const float4 b,
                              bf16x8& hi, bf16x8& lo) {
  float v[8] = {a.x, a.y, a.z, a.w, b.x, b.y, b.z, b.w};
#pragma unroll
  for (int i = 0; i < 8; ++i) {
    const unsigned short h = bf_rne(v[i]);
    hi[i] = (short)h;
    lo[i] = (short)bf_rne(v[i] - bf2f((short)h));
  }
}
// combined-layout fragment load: off is an 8-short-aligned element offset in
// the logical [row][64] space; hi at 2*off, lo at 2*off+8.
#define LDHL(dh_, dl_, base_, off_)                                            \
  do {                                                                         \
    const size_t o2_ = ((size_t)(off_)) << 1;                                  \
    dh_ = *(const bf16x8*)((base_) + o2_);                                     \
    dl_ = *(const bf16x8*)((base_) + o2_ + 8);                                 \
  } while (0)

// 3-chain split-bf16 64-apply: A rows from global hi/lo, B slice from LDS ptr.
__device__ inline f32x4 apply3(const short* __restrict__ mh_,
                               const short* __restrict__ ml_,
                               const float* __restrict__ brow, int lg) {
  f32x4 o = (f32x4)0.f;
#pragma unroll
  for (int ks = 0; ks < 2; ++ks) {
    const bf16x8 mh = *(const bf16x8*)(mh_ + ks * 32 + lg * 8);
    const bf16x8 ml = *(const bf16x8*)(ml_ + ks * 32 + lg * 8);
    const float* bp = brow + ks * 32 + lg * 8;
    bf16x8 bh, bl;
    split8(*(const float4*)bp, *(const float4*)(bp + 4), bh, bl);
    o = __builtin_amdgcn_mfma_f32_16x16x32_bf16(mh, bh, o, 0, 0, 0);
    o = __builtin_amdgcn_mfma_f32_16x16x32_bf16(ml, bh, o, 0, 0, 0);
    o = __builtin_amdgcn_mfma_f32_16x16x32_bf16(mh, bl, o, 0, 0, 0);
  }
  return o;
}

// ---------------------------------------------------------------------------
// Fused pre-GEMM splits: hs -> Ahi/Alo, Wqkv -> Whi/Wlo.
// ---------------------------------------------------------------------------
__global__ __launch_bounds__(256) void split_pre(
    const float* __restrict__ hs, short* __restrict__ h1, short* __restrict__ l1,
    const float* __restrict__ wq, short* __restrict__ h2, short* __restrict__ l2) {
  const int n1 = B * S * HID / 4;
  const int n2 = 3 * HID * HID / 4;
  for (int g = blockIdx.x * 256 + threadIdx.x; g < n1 + n2; g += gridDim.x * 256) {
    const bool first = g < n1;
    const int idx = first ? g : g - n1;
    const float4 x = first ? *(const float4*)(hs + (size_t)idx * 4)
                           : *(const float4*)(wq + (size_t)idx * 4);
    short4 h, l;
    h.x = bf_rne(x.x); h.y = bf_rne(x.y); h.z = bf_rne(x.z); h.w = bf_rne(x.w);
    l.x = bf_rne(x.x - bf2f(h.x));
    l.y = bf_rne(x.y - bf2f(h.y));
    l.z = bf_rne(x.z - bf2f(h.z));
    l.w = bf_rne(x.w - bf2f(h.w));
    if (first) {
      *(short4*)(h1 + (size_t)idx * 4) = h;
      *(short4*)(l1 + (size_t)idx * 4) = l;
    } else {
      *(short4*)(h2 + (size_t)idx * 4) = h;
      *(short4*)(l2 + (size_t)idx * 4) = l;
    }
  }
}

// ---------------------------------------------------------------------------
// Fused post-scan splits: Abuf (gathered) -> A2hi/A2lo, Wd -> Wdhi/Wdlo.
// ---------------------------------------------------------------------------
__global__ __launch_bounds__(256) void split_post(
    const float* __restrict__ Abuf, short* __restrict__ h1, short* __restrict__ l1,
    const float* __restrict__ wd, short* __restrict__ h2, short* __restrict__ l2) {
  const int n1 = B * S * HID / 4;
  const int n2 = HID * HID / 4;
  for (int g = blockIdx.x * 256 + threadIdx.x; g < n1 + n2; g += gridDim.x * 256) {
    float4 x;
    if (g < n1) {
      const int m = g >> 8, q = g & 255;
      const int k0 = q * 4;
      const int b = m >> 11, s = m & (S - 1);
      const int h = k0 >> 6, d = k0 & 63;
      x = *(const float4*)(Abuf + (((size_t)(b * NH + h) * S + s) << 6) + d);
    } else {
      x = *(const float4*)(wd + (size_t)(g - n1) * 4);
    }
    short4 h, l;
    h.x = bf_rne(x.x); h.y = bf_rne(x.y); h.z = bf_rne(x.z); h.w = bf_rne(x.w);
    l.x = bf_rne(x.x - bf2f(h.x));
    l.y = bf_rne(x.y - bf2f(h.y));
    l.z = bf_rne(x.z - bf2f(h.z));
    l.w = bf_rne(x.w - bf2f(h.w));
    if (g < n1) {
      *(short4*)(h1 + (size_t)g * 4) = h;
      *(short4*)(l1 + (size_t)g * 4) = l;
    } else {
      *(short4*)(h2 + (size_t)(g - n1) * 4) = h;
      *(short4*)(l2 + (size_t)(g - n1) * 4) = l;
    }
  }
}

// ---------------------------------------------------------------------------
// Split-bf16 MFMA NT GEMM (fp32 via 3 bf16 chains), register-staged prefetch
// + XCD swizzle.  MODE 0: C = A@B^T + bias (fp32 out).
// MODE 1 (QKV): epilogue applies bias + RoPE (shfl partner) + Q-scale and
// scatters into COMBINED hi|lo Qc/Kc layout (hi+lo same 64B sector) + fp32 V.
// ---------------------------------------------------------------------------
template<int MODE>
__global__ __launch_bounds__(256) void gemm_bf3(
    const short* __restrict__ Ahi, const short* __restrict__ Alo,
    const short* __restrict__ Bhi, const short* __restrict__ Blo,
    const float* __restrict__ bias, float* __restrict__ C,
    short* __restrict__ Qc, short* __restrict__ Kc,
    float* __restrict__ Vb, int M, int N, int K) {
  __shared__ short ash[128][40], als[128][40], bsh[128][40], bls[128][40];
  const int t = threadIdx.x;
  const int nwg = gridDim.x * gridDim.y;
  const int wg0 = blockIdx.y * gridDim.x + blockIdx.x;
  const int cpx = nwg >> 3;
  const int wg  = (wg0 & 7) * cpx + (wg0 >> 3);
  const int m0 = (wg / gridDim.x) * 128, n0 = (wg % gridDim.x) * 128;
  const int w = t >> 6, l = t & 63;
  const int wm = (w >> 1) * 64, wn = (w & 1) * 64;
  const int lr = l & 15, lk = (l >> 4) * 8;
  const int row0 = t >> 2,        c80 = (t & 3) * 8;
  const int row1 = (t + 256) >> 2, c81 = ((t + 256) & 3) * 8;

  f32x4 acc[4][4];
#pragma unroll
  for (int i = 0; i < 4; ++i)
#pragma unroll
    for (int j = 0; j < 4; ++j) acc[i][j] = (f32x4)0.f;

  uint4 rah0, rah1, ral0, ral1, rbh0, rbh1, rbl0, rbl1;
#define GLOAD(kb)                                                              \
  do {                                                                         \
    rah0 = *(const uint4*)(Ahi + (size_t)(m0 + row0) * K + (kb) + c80);        \
    rah1 = *(const uint4*)(Ahi + (size_t)(m0 + row1) * K + (kb) + c81);        \
    ral0 = *(const uint4*)(Alo + (size_t)(m0 + row0) * K + (kb) + c80);        \
    ral1 = *(const uint4*)(Alo + (size_t)(m0 + row1) * K + (kb) + c81);        \
    rbh0 = *(const uint4*)(Bhi + (size_t)(n0 + row0) * K + (kb) + c80);        \
    rbh1 = *(const uint4*)(Bhi + (size_t)(n0 + row1) * K + (kb) + c81);        \
    rbl0 = *(const uint4*)(Blo + (size_t)(n0 + row0) * K + (kb) + c80);        \
    rbl1 = *(const uint4*)(Blo + (size_t)(n0 + row1) * K + (kb) + c81);        \
  } while (0)

  GLOAD(0);
  for (int kb = 0; kb < K; kb += 32) {
    __syncthreads();
    *(uint4*)&ash[row0][c80] = rah0; *(uint4*)&ash[row1][c81] = rah1;
    *(uint4*)&als[row0][c80] = ral0; *(uint4*)&als[row1][c81] = ral1;
    *(uint4*)&bsh[row0][c80] = rbh0; *(uint4*)&bsh[row1][c81] = rbh1;
    *(uint4*)&bls[row0][c80] = rbl0; *(uint4*)&bls[row1][c81] = rbl1;
    __syncthreads();
    if (kb + 32 < K) GLOAD(kb + 32);
    bf16x8 ah[4], al[4], bh[4], bl[4];
#pragma unroll
    for (int mi = 0; mi < 4; ++mi) {
      ah[mi] = *(const bf16x8*)&ash[wm + mi * 16 + lr][lk];
      al[mi] = *(const bf16x8*)&als[wm + mi * 16 + lr][lk];
    }
#pragma unroll
    for (int ni = 0; ni < 4; ++ni) {
      bh[ni] = *(const bf16x8*)&bsh[wn + ni * 16 + lr][lk];
      bl[ni] = *(const bf16x8*)&bls[wn + ni * 16 + lr][lk];
    }
#pragma unroll
    for (int mi = 0; mi < 4; ++mi)
#pragma unroll
      for (int ni = 0; ni < 4; ++ni) {
        acc[mi][ni] = __builtin_amdgcn_mfma_f32_16x16x32_bf16(
            ah[mi], bh[ni], acc[mi][ni], 0, 0, 0);
        acc[mi][ni] = __builtin_amdgcn_mfma_f32_16x16x32_bf16(
            al[mi], bh[ni], acc[mi][ni], 0, 0, 0);
        acc[mi][ni] = __builtin_amdgcn_mfma_f32_16x16x32_bf16(
            ah[mi], bl[ni], acc[mi][ni], 0, 0, 0);
      }
  }
#undef GLOAD
  const int rq = (l >> 4) * 4;
  if (MODE == 0) {
#pragma unroll
    for (int ni = 0; ni < 4; ++ni) {
      const int col = n0 + wn + ni * 16 + lr;
      const float bv = bias[col];
#pragma unroll
      for (int mi = 0; mi < 4; ++mi)
#pragma unroll
        for (int r = 0; r < 4; ++r) {
          const int row = m0 + wm + mi * 16 + rq + r;
          C[(size_t)row * N + col] = acc[mi][ni][r] + bv;
        }
    }
  } else {
    // fused QKV epilogue (R17 scatter, combined hi|lo layout)
    const float PW[8] = {1.0f, 3.1622776601683795f, 10.0f, 31.622776601683793f,
                         100.0f, 316.22776601683796f, 1000.0f, 3162.2776601683795f};
#pragma unroll
    for (int ni = 0; ni < 4; ++ni) {
      const int col = n0 + wn + ni * 16 + lr;
      const float bv = bias[col];
      const int which = col >> 10;       // 0 Q, 1 K, 2 V (wave-uniform)
      const int d = col & 63;
      const int hh = (col >> 6) & 15;    // wave-uniform
      const bool rot = (which < 2) && (d < 16);
      const float invf = 1.0f / PW[d & 7];
#pragma unroll
      for (int mi = 0; mi < 4; ++mi)
#pragma unroll
        for (int r = 0; r < 4; ++r) {
          const int row = m0 + wm + mi * 16 + rq + r;
          const int b = row >> 11, sidx = row & (S - 1);
          float val = acc[mi][ni][r] + bv;
          const float pv = __shfl_xor(val, 8, 64);   // rotate-half partner
          if (rot) {
            float sn, cs;
            sincosf((float)sidx * invf, &sn, &cs);
            val = val * cs + ((d < 8) ? -pv : pv) * sn;
          }
          const size_t o = (((size_t)(b * NH + hh) * S + sidx) << 6) + d;
          if (which == 2) {
            Vb[o] = val;
          } else {
            if (which == 0) val *= 0.125f;
            const unsigned short hv = bf_rne(val);
            short* dc = (which == 0) ? Qc : Kc;
            const size_t hidx = ((o & ~(size_t)7) << 1) + (d & 7);
            dc[hidx] = (short)hv;
            dc[hidx + 8] = (short)bf_rne(val - bf2f((short)hv));
          }
        }
    }
  }
}

// ---------------------------------------------------------------------------
// MFMA score pass: Q fragments direct from global (combined layout); K staged
// in LDS.
// ---------------------------------------------------------------------------
__global__ __launch_bounds__(256) void k3_scores(
    const short* __restrict__ Qc, const short* __restrict__ Kc,
    float* __restrict__ partZ, float* __restrict__ sdg) {
  const int cb = blockIdx.x, rb = blockIdx.y, bh = blockIdx.z;
  if (cb > rb) return;
  __shared__ short kh[128][72], kl[128][72];
  __shared__ float red[128][2];
  const int t = threadIdx.x;
  const int w = t >> 6, l = t & 63;
  const int wm = (w >> 1) * 64, wn = (w & 1) * 64;
  const int lr = l & 15, lg = l >> 4;
  for (int v = t; v < 1024; v += 256) {
    const int r = v >> 3, c8 = (v & 7) * 8;
    const size_t gk = (((size_t)bh * S + cb * 128 + r) << 6) + c8;
    *(uint4*)&kh[r][c8] = *(const uint4*)(Kc + (gk << 1));
    *(uint4*)&kl[r][c8] = *(const uint4*)(Kc + (gk << 1) + 8);
  }
  __syncthreads();
  f32x4 acc[4][4];
#pragma unroll
  for (int i = 0; i < 4; ++i)
#pragma unroll
    for (int j = 0; j < 4; ++j) acc[i][j] = (f32x4)0.f;
#pragma unroll
  for (int ks = 0; ks < 2; ++ks) {
    const int lk = ks * 32 + lg * 8;
    bf16x8 ah[4], al[4], bhf[4], blf[4];
#pragma unroll
    for (int mi = 0; mi < 4; ++mi) {
      const size_t qo = (((size_t)bh * S + rb * 128 + wm + mi * 16 + lr) << 6) + lk;
      LDHL(ah[mi], al[mi], Qc, qo);
    }
#pragma unroll
    for (int ni = 0; ni < 4; ++ni) {
      bhf[ni] = *(const bf16x8*)&kh[wn + ni * 16 + lr][lk];
      blf[ni] = *(const bf16x8*)&kl[wn + ni * 16 + lr][lk];
    }
#pragma unroll
    for (int mi = 0; mi < 4; ++mi)
#pragma unroll
      for (int ni = 0; ni < 4; ++ni) {
        acc[mi][ni] = __builtin_amdgcn_mfma_f32_16x16x32_bf16(
            ah[mi], bhf[ni], acc[mi][ni], 0, 0, 0);
        acc[mi][ni] = __builtin_amdgcn_mfma_f32_16x16x32_bf16(
            al[mi], bhf[ni], acc[mi][ni], 0, 0, 0);
        acc[mi][ni] = __builtin_amdgcn_mfma_f32_16x16x32_bf16(
            ah[mi], blf[ni], acc[mi][ni], 0, 0, 0);
      }
  }
  const int rq = lg * 4;
  const int rowbase = rb * 128 + wm, colbase = cb * 128 + wn;
  float rp[4][4];
#pragma unroll
  for (int mi = 0; mi < 4; ++mi)
#pragma unroll
    for (int r = 0; r < 4; ++r) rp[mi][r] = 0.f;
#pragma unroll
  for (int mi = 0; mi < 4; ++mi)
#pragma unroll
    for (int ni = 0; ni < 4; ++ni)
#pragma unroll
      for (int r = 0; r < 4; ++r) {
        const int rG = rowbase + mi * 16 + rq + r;
        const int cG = colbase + ni * 16 + lr;
        if (cG <= rG) rp[mi][r] += __expf(acc[mi][ni][r]);
        if (cG == rG) sdg[(size_t)bh * S + rG] = acc[mi][ni][r];
      }
#pragma unroll
  for (int off = 1; off < 16; off <<= 1)
#pragma unroll
    for (int mi = 0; mi < 4; ++mi)
#pragma unroll
      for (int r = 0; r < 4; ++r)
        rp[mi][r] += __shfl_xor(rp[mi][r], off, 64);
  if (lr == 0)
#pragma unroll
    for (int mi = 0; mi < 4; ++mi)
#pragma unroll
      for (int r = 0; r < 4; ++r)
        red[wm + mi * 16 + rq + r][w & 1] = rp[mi][r];
  __syncthreads();
  if (t < 128)
    partZ[(((size_t)bh * 16 + rb) * 16 + cb) * 128 + t] = red[t][0] + red[t][1];
}

// ---------------------------------------------------------------------------
__global__ __launch_bounds__(256) void k3_reduce(
    const float* __restrict__ partZ, float* __restrict__ zinv,
    float* __restrict__ pdg) {
  const int R = blockIdx.x * 256 + threadIdx.x;
  const int bh = R >> 11, r = R & 2047;
  const int rb = r >> 7, row = r & 127;
  float Z = 0.f;
  for (int c = 0; c <= rb; ++c)
    Z += partZ[(((size_t)bh*16 + rb)*16 + c)*128 + row];
  const float zi = 1.f / Z;
  zinv[R] = zi;
  pdg[R] = __expf(pdg[R]) * zi;
}

// ---------------------------------------------------------------------------
// Per-64-block unit-lower-triangular inverse of (I - N), 256 threads.
// ---------------------------------------------------------------------------
__global__ __launch_bounds__(256) void k4_minv(
    const short* __restrict__ Qc, const short* __restrict__ Kc,
    const float* __restrict__ zinv, short* __restrict__ Mrh,
    short* __restrict__ Mrl, short* __restrict__ P10h,
    short* __restrict__ P10l) {
  const int bh = blockIdx.y, ib = blockIdx.x;
  const int r0 = ib * 64;
  __shared__ float Nb[64][68];
  __shared__ float X[64][68];
  const int t = threadIdx.x;
  const int w = t >> 6, l = t & 63;
  const int lr = l & 15, lg = l >> 4;

  bf16x8 qfh[2], qfl[2];
  const size_t qbase = (((size_t)bh * S + r0 + 16 * w + lr) << 6);
#pragma unroll
  for (int ks = 0; ks < 2; ++ks)
    LDHL(qfh[ks], qfl[ks], Qc, qbase + ks * 32 + lg * 8);
  const int rloc0 = 16 * w + lg * 4;
  float ziv[4];
#pragma unroll
  for (int i = 0; i < 4; ++i) ziv[i] = zinv[(size_t)bh * S + r0 + rloc0 + i];

  {
    f32x4 acc[4];
#pragma unroll
    for (int i = 0; i < 4; ++i) acc[i] = (f32x4)0.f;
    const size_t kbase = ((size_t)bh * S + r0) << 6;
#pragma unroll
    for (int ks = 0; ks < 2; ++ks) {
#pragma unroll
      for (int ni = 0; ni < 4; ++ni) {
        const size_t kb = kbase + (((size_t)(16 * ni + lr)) << 6) + ks * 32 + lg * 8;
        bf16x8 bhf, blf;
        LDHL(bhf, blf, Kc, kb);
        acc[ni] = __builtin_amdgcn_mfma_f32_16x16x32_bf16(qfh[ks], bhf, acc[ni], 0, 0, 0);
        acc[ni] = __builtin_amdgcn_mfma_f32_16x16x32_bf16(qfl[ks], bhf, acc[ni], 0, 0, 0);
        acc[ni] = __builtin_amdgcn_mfma_f32_16x16x32_bf16(qfh[ks], blf, acc[ni], 0, 0, 0);
      }
    }
#pragma unroll
    for (int ni = 0; ni < 4; ++ni) {
      const int c = 16 * ni + lr;
#pragma unroll
      for (int i = 0; i < 4; ++i) {
        const int r = rloc0 + i;
        Nb[r][c] = (c < r) ? __expf(acc[ni][i]) * ziv[i] : 0.f;
      }
    }
  }
  if (ib & 1) {
    f32x4 p[4];
#pragma unroll
    for (int i = 0; i < 4; ++i) p[i] = (f32x4)0.f;
    const size_t kbase = ((size_t)bh * S + r0 - 64) << 6;
#pragma unroll
    for (int ks = 0; ks < 2; ++ks) {
#pragma unroll
      for (int ni = 0; ni < 4; ++ni) {
        const size_t kb = kbase + (((size_t)(16 * ni + lr)) << 6) + ks * 32 + lg * 8;
        bf16x8 bhf, blf;
        LDHL(bhf, blf, Kc, kb);
        p[ni] = __builtin_amdgcn_mfma_f32_16x16x32_bf16(qfh[ks], bhf, p[ni], 0, 0, 0);
        p[ni] = __builtin_amdgcn_mfma_f32_16x16x32_bf16(qfl[ks], bhf, p[ni], 0, 0, 0);
        p[ni] = __builtin_amdgcn_mfma_f32_16x16x32_bf16(qfh[ks], blf, p[ni], 0, 0, 0);
      }
    }
    const size_t pbase = (((size_t)bh * 16 + (ib >> 1)) * 64) * 64;
#pragma unroll
    for (int ni = 0; ni < 4; ++ni) {
      const int c = 16 * ni + lr;
#pragma unroll
      for (int i = 0; i < 4; ++i) {
        const float val = __expf(p[ni][i]) * ziv[i];
        const unsigned short h = bf_rne(val);
        P10h[pbase + (size_t)(rloc0 + i) * 64 + c] = (short)h;
        P10l[pbase + (size_t)(rloc0 + i) * 64 + c] = (short)bf_rne(val - bf2f((short)h));
      }
    }
  }
  {
    const int c = t & 63, g = t >> 6;
#pragma unroll
    for (int i = 0; i < 16; ++i) {
      const int r = 16 * g + i;
      X[r][c] = (r == c) ? 1.f : 0.f;
    }
  }
  __syncthreads();

  const int c = t & 63, g = t >> 6;
  if (w == 0) {
    for (int rr = 1; rr < 16; ++rr) {
      float a = 0.f;
      for (int j = 0; j < rr; ++j) a += Nb[rr][j] * X[j][l];
      X[rr][l] += a;
    }
  }
  __syncthreads();
#pragma unroll
  for (int I = 1; I < 4; ++I) {
    {
      const int rb4 = 16 * I + 4 * g;
      float s0 = 0.f, s1 = 0.f, s2 = 0.f, s3 = 0.f;
      for (int j = 0; j < 16 * I; j += 4) {
        const float4 n0 = *(const float4*)&Nb[rb4 + 0][j];
        const float4 n1 = *(const float4*)&Nb[rb4 + 1][j];
        const float4 n2 = *(const float4*)&Nb[rb4 + 2][j];
        const float4 n3 = *(const float4*)&Nb[rb4 + 3][j];
        const float x0 = X[j + 0][c], x1 = X[j + 1][c];
        const float x2 = X[j + 2][c], x3 = X[j + 3][c];
        s0 += n0.x * x0 + n0.y * x1 + n0.z * x2 + n0.w * x3;
        s1 += n1.x * x0 + n1.y * x1 + n1.z * x2 + n1.w * x3;
        s2 += n2.x * x0 + n2.y * x1 + n2.z * x2 + n2.w * x3;
        s3 += n3.x * x0 + n3.y * x1 + n3.z * x2 + n3.w * x3;
      }
      X[rb4 + 0][c] += s0; X[rb4 + 1][c] += s1;
      X[rb4 + 2][c] += s2; X[rb4 + 3][c] += s3;
    }
    __syncthreads();
    if (w == 0) {
      const int rb = 16 * I;
      for (int rr = 1; rr < 16; ++rr) {
        const int r = rb + rr;
        float a = 0.f;
        for (int j = rb; j < r; ++j) a += Nb[r][j] * X[j][l];
        X[r][l] += a;
      }
    }
    __syncthreads();
  }

  const size_t mb = (((size_t)bh * 32 + ib) * 64) * 64;
  for (int v = t; v < 4096; v += 256) {
    const int r = v >> 6, cc = v & 63;
    const float x = X[r][cc];
    const unsigned short h = bf_rne(x);
    Mrh[mb + v] = (short)h;
    Mrl[mb + v] = (short)bf_rne(x - bf2f((short)h));
  }
}

// ---------------------------------------------------------------------------
// Scan step s (256 rows) off-diagonal accumulate, FULL MFMA, XCD-paired grid.
// ---------------------------------------------------------------------------
__global__ __launch_bounds__(256) void k5_acc(
    const short* __restrict__ Qc, const short* __restrict__ Kc,
    const float* __restrict__ Abuf, const float* __restrict__ zinv,
    float* __restrict__ up, int s) {
  __shared__ float Es[128][68];
  __shared__ float Ats[64][68];
  const int x = blockIdx.x;
  const int ng = gridDim.x >> 6;           // /(2*BH)
  const int p = ((x >> 4) << 3) + (x & 7); // pair index
  const int rh = (x >> 3) & 1;
  const int g = p % ng;
  const int bh = p / ng;
  const int t = threadIdx.x;
  const int w = t >> 6, l = t & 63;
  const int lr = l & 15, lg = l >> 4;
  const int rw = 32 * w;
  const int base = s * 256 + rh * 128;

  bf16x8 qfh[2][2], qfl[2][2];
#pragma unroll
  for (int mi = 0; mi < 2; ++mi)
#pragma unroll
    for (int ks = 0; ks < 2; ++ks) {
      const size_t qo = (((size_t)bh * S + base + rw + mi * 16 + lr) << 6) + ks * 32 + lg * 8;
      LDHL(qfh[mi][ks], qfl[mi][ks], Qc, qo);
    }
  float ziv[2][4];
#pragma unroll
  for (int mi = 0; mi < 2; ++mi)
#pragma unroll
    for (int r = 0; r < 4; ++r)
      ziv[mi][r] = zinv[(size_t)bh * S + base + rw + mi * 16 + lg * 4 + r];

  f32x4 out[2][4];
#pragma unroll
  for (int mi = 0; mi < 2; ++mi)
#pragma unroll
    for (int ni = 0; ni < 4; ++ni) out[mi][ni] = (f32x4)0.f;

  for (int j = g; j < 2 * s; j += ng) {
    for (int h = 0; h < 2; ++h) {
      __syncthreads();
      for (int v = t; v < 1024; v += 256) {
        const int d = v & 63, sq = v >> 6;
        const size_t ab = ((size_t)bh * S + j * 128 + h * 64 + sq * 4) << 6;
        float4 o;
        o.x = Abuf[ab + d];
        o.y = Abuf[ab + 64 + d];
        o.z = Abuf[ab + 128 + d];
        o.w = Abuf[ab + 192 + d];
        *(float4*)&Ats[d][sq * 4] = o;
      }
      f32x4 qk[2][4];
#pragma unroll
      for (int mi = 0; mi < 2; ++mi)
#pragma unroll
        for (int ni = 0; ni < 4; ++ni) qk[mi][ni] = (f32x4)0.f;
#pragma unroll
      for (int ks = 0; ks < 2; ++ks) {
#pragma unroll
        for (int ni = 0; ni < 4; ++ni) {
          const size_t ko = (((size_t)bh * S + j * 128 + h * 64 + ni * 16 + lr) << 6) + ks * 32 + lg * 8;
          bf16x8 kh8, kl8;
          LDHL(kh8, kl8, Kc, ko);
#pragma unroll
          for (int mi = 0; mi < 2; ++mi) {
            qk[mi][ni] = __builtin_amdgcn_mfma_f32_16x16x32_bf16(
                qfh[mi][ks], kh8, qk[mi][ni], 0, 0, 0);
            qk[mi][ni] = __builtin_amdgcn_mfma_f32_16x16x32_bf16(
                qfl[mi][ks], kh8, qk[mi][ni], 0, 0, 0);
            qk[mi][ni] = __builtin_amdgcn_mfma_f32_16x16x32_bf16(
                qfh[mi][ks], kl8, qk[mi][ni], 0, 0, 0);
          }
        }
      }
#pragma unroll
      for (int mi = 0; mi < 2; ++mi)
#pragma unroll
        for (int ni = 0; ni < 4; ++ni)
#pragma unroll
          for (int r = 0; r < 4; ++r)
            Es[rw + mi * 16 + lg * 4 + r][ni * 16 + lr] =
                __expf(qk[mi][ni][r]) * ziv[mi][r];
      __syncthreads();
#pragma unroll
      for (int ks = 0; ks < 2; ++ks) {
        bf16x8 eh[2], el[2];
#pragma unroll
        for (int mi = 0; mi < 2; ++mi) {
          const float* ep = &Es[rw + mi * 16 + lr][ks * 32 + lg * 8];
          split8(*(const float4*)ep, *(const float4*)(ep + 4), eh[mi], el[mi]);
        }
#pragma unroll
        for (int ni = 0; ni < 4; ++ni) {
          const float* ap = &Ats[ni * 16 + lr][ks * 32 + lg * 8];
          bf16x8 ah8, al8;
          split8(*(const float4*)ap, *(const float4*)(ap + 4), ah8, al8);
#pragma unroll
          for (int mi = 0; mi < 2; ++mi) {
            out[mi][ni] = __builtin_amdgcn_mfma_f32_16x16x32_bf16(
                eh[mi], ah8, out[mi][ni], 0, 0, 0);
            out[mi][ni] = __builtin_amdgcn_mfma_f32_16x16x32_bf16(
                el[mi], ah8, out[mi][ni], 0, 0, 0);
            out[mi][ni] = __builtin_amdgcn_mfma_f32_16x16x32_bf16(
                eh[mi], al8, out[mi][ni], 0, 0, 0);
          }
        }
      }
    }
  }
  float* ub = up + (((size_t)(bh * 7 + g) * 2 + rh) << 13);
#pragma unroll
  for (int mi = 0; mi < 2; ++mi)
#pragma unroll
    for (int ni = 0; ni < 4; ++ni)
#pragma unroll
      for (int r = 0; r < 4; ++r)
        ub[(size_t)(rw + mi * 16 + lg * 4 + r) * 64 + ni * 16 + lr] =
            out[mi][ni][r];
}

// ---------------------------------------------------------------------------
// Scan step s finalize (256 rows), grid (4, BH), d-quads of 16.
// ---------------------------------------------------------------------------
__global__ __launch_bounds__(256) void k5_fin(
    const short* __restrict__ Qc, const short* __restrict__ Kc,
    const float* __restrict__ V, const float* __restrict__ pd,
    const float* __restrict__ zinv, const float* __restrict__ up,
    const short* __restrict__ Mrh, const short* __restrict__ Mrl,
    const short* __restrict__ P10h, const short* __restrict__ P10l,
    float* __restrict__ Abuf, int s) {
  const int d0 = blockIdx.x * 16;
  const int bh = blockIdx.y;
  const int t = threadIdx.x;
  const int w = t >> 6, l = t & 63;
  const int lr = l & 15, lg = l >> 4;
  const int base = s * 256;
  __shared__ float uT[16][260];
  __shared__ float aT[16][132];
  __shared__ float Es[128][68];
  const int ng = (2 * s < 7) ? 2 * s : 7;

  for (int v = t; v < 1024; v += 256) {
    const int r = v >> 2, f = v & 3;
    const int R = base + r;
    const float4 x = *(const float4*)(V + (((size_t)bh * S + R) << 6) + d0 + f * 4);
    const float p = pd[(size_t)bh * S + R];
    float a0 = p * x.x, a1 = p * x.y, a2 = p * x.z, a3 = p * x.w;
    const int rh = r >> 7, rr = r & 127;
    for (int g = 0; g < ng; ++g) {
      const float4 y = *(const float4*)(
          up + (((size_t)(bh * 7 + g) * 2 + rh) << 13) + (rr << 6) + d0 + f * 4);
      a0 += y.x; a1 += y.y; a2 += y.z; a3 += y.w;
    }
    uT[f * 4 + 0][r] = a0; uT[f * 4 + 1][r] = a1;
    uT[f * 4 + 2][r] = a2; uT[f * 4 + 3][r] = a3;
  }
  __syncthreads();
  const size_t mstep = (size_t)bh * 32 + s * 4;
  {
    const size_t mb = ((mstep + 0) * 64 + 16 * w + lr) * 64;
    const f32x4 o = apply3(Mrh + mb, Mrl + mb, &uT[lr][0], lg);
#pragma unroll
    for (int i = 0; i < 4; ++i) {
      const int r = 16 * w + lg * 4 + i;
      Abuf[(((size_t)bh * S + base + r) << 6) + d0 + lr] = o[i];
      aT[lr][r] = o[i];
    }
  }
  __syncthreads();
  {
    const size_t pb = (((size_t)bh * 16 + 2 * s) * 64 + 16 * w + lr) * 64;
    const f32x4 o = apply3(P10h + pb, P10l + pb, &aT[lr][0], lg);
#pragma unroll
    for (int i = 0; i < 4; ++i)
      uT[lr][64 + 16 * w + lg * 4 + i] += o[i];
  }
  __syncthreads();
  {
    const size_t mb = ((mstep + 1) * 64 + 16 * w + lr) * 64;
    const f32x4 o = apply3(Mrh + mb, Mrl + mb, &uT[lr][64], lg);
#pragma unroll
    for (int i = 0; i < 4; ++i) {
      const int r = 16 * w + lg * 4 + i;
      Abuf[(((size_t)bh * S + base + 64 + r) << 6) + d0 + lr] = o[i];
      aT[lr][64 + r] = o[i];
    }
  }
  {
    const int rw = 32 * w;
    bf16x8 qh_[2][2], ql_[2][2];
#pragma unroll
    for (int mi = 0; mi < 2; ++mi)
#pragma unroll
      for (int ks = 0; ks < 2; ++ks) {
        const size_t qo = (((size_t)bh * S + base + 128 + rw + mi * 16 + lr) << 6) + ks * 32 + lg * 8;
        LDHL(qh_[mi][ks], ql_[mi][ks], Qc, qo);
      }
    float zv[2][4];
#pragma unroll
    for (int mi = 0; mi < 2; ++mi)
#pragma unroll
      for (int i = 0; i < 4; ++i)
        zv[mi][i] = zinv[(size_t)bh * S + base + 128 + rw + mi * 16 + lg * 4 + i];
    for (int ch = 0; ch < 2; ++ch) {
      __syncthreads();
      f32x4 qk[2][4];
#pragma unroll
      for (int mi = 0; mi < 2; ++mi)
#pragma unroll
        for (int ni = 0; ni < 4; ++ni) qk[mi][ni] = (f32x4)0.f;
#pragma unroll
      for (int ks = 0; ks < 2; ++ks) {
#pragma unroll
        for (int ni = 0; ni < 4; ++ni) {
          const size_t ko = (((size_t)bh * S + base + ch * 64 + ni * 16 + lr) << 6) + ks * 32 + lg * 8;
          bf16x8 kh8, kl8;
          LDHL(kh8, kl8, Kc, ko);
#pragma unroll
          for (int mi = 0; mi < 2; ++mi) {
            qk[mi][ni] = __builtin_amdgcn_mfma_f32_16x16x32_bf16(
                qh_[mi][ks], kh8, qk[mi][ni], 0, 0, 0);
            qk[mi][ni] = __builtin_amdgcn_mfma_f32_16x16x32_bf16(
                ql_[mi][ks], kh8, qk[mi][ni], 0, 0, 0);
            qk[mi][ni] = __builtin_amdgcn_mfma_f32_16x16x32_bf16(
                qh_[mi][ks], kl8, qk[mi][ni], 0, 0, 0);
          }
        }
      }
#pragma unroll
      for (int mi = 0; mi < 2; ++mi)
#pragma unroll
        for (int ni = 0; ni < 4; ++ni)
#pragma unroll
          for (int i = 0; i < 4; ++i)
            Es[rw + mi * 16 + lg * 4 + i][ni * 16 + lr] =
                __expf(qk[mi][ni][i]) * zv[mi][i];
      __syncthreads();
#pragma unroll
      for (int mi = 0; mi < 2; ++mi) {
        f32x4 o = (f32x4)0.f;
#pragma unroll
        for (int kq = 0; kq < 2; ++kq) {
          const float* ep = &Es[rw + mi * 16 + lr][kq * 32 + lg * 8];
          bf16x8 eh, el;
          split8(*(const float4*)ep, *(const float4*)(ep + 4), eh, el);
          const float* ap = &aT[lr][ch * 64 + kq * 32 + lg * 8];
          bf16x8 ah, al;
          split8(*(const float4*)ap, *(const float4*)(ap + 4), ah, al);
          o = __builtin_amdgcn_mfma_f32_16x16x32_bf16(eh, ah, o, 0, 0, 0);
          o = __builtin_amdgcn_mfma_f32_16x16x32_bf16(el, ah, o, 0, 0, 0);
          o = __builtin_amdgcn_mfma_f32_16x16x32_bf16(eh, al, o, 0, 0, 0);
        }
#pragma unroll
        for (int i = 0; i < 4; ++i)
          uT[lr][128 + rw + mi * 16 + lg * 4 + i] += o[i];
      }
    }
  }
  __syncthreads();
  {
    const size_t mb = ((mstep + 2) * 64 + 16 * w + lr) * 64;
    const f32x4 o = apply3(Mrh + mb, Mrl + mb, &uT[lr][128], lg);
#pragma unroll
    for (int i = 0; i < 4; ++i) {
      const int r = 16 * w + lg * 4 + i;
      Abuf[(((size_t)bh * S + base + 128 + r) << 6) + d0 + lr] = o[i];
      aT[lr][r] = o[i];
    }
  }
  __syncthreads();
  {
    const size_t pb = (((size_t)bh * 16 + 2 * s + 1) * 64 + 16 * w + lr) * 64;
    const f32x4 o = apply3(P10h + pb, P10l + pb, &aT[lr][0], lg);
#pragma unroll
    for (int i = 0; i < 4; ++i)
      uT[lr][192 + 16 * w + lg * 4 + i] += o[i];
  }
  __syncthreads();
  {
    const size_t mb = ((mstep + 3) * 64 + 16 * w + lr) * 64;
    const f32x4 o = apply3(Mrh + mb, Mrl + mb, &uT[lr][192], lg);
#pragma unroll
    for (int i = 0; i < 4; ++i) {
      const int r = 16 * w + lg * 4 + i;
      Abuf[(((size_t)bh * S + base + 192 + r) << 6) + d0 + lr] = o[i];
    }
  }
}

} // namespace

extern "C" void kernel_launch(void* const* d_in, const int* in_sizes, int n_in,
                              void* d_out, int out_size, void* d_ws, size_t ws_size,
                              hipStream_t stream) {
  const float* hs   = (const float*)d_in[0];
  const float* Wqkv = (const float*)d_in[1];
  const float* bqkv = (const float*)d_in[2];
  const float* Wd   = (const float*)d_in[3];
  const float* bd   = (const float*)d_in[4];
  float* out = (float*)d_out;
  float* W   = (float*)d_ws;
  if (ws_size < WS_FLOATS * sizeof(float)) return;  // insufficient scratch

  float* partZ = W;               // transient (scores->reduce)
  float* Abuf  = W + OFF_A;
  short* Qc    = (short*)(W + OFF_Q);   // combined hi|lo, 16MB
  short* Kc    = (short*)(W + OFF_K);   // combined hi|lo, 16MB
  float* Vb    = W + OFF_V;
  float* zi    = W + OFF_ZI;
  float* pdg   = W + OFF_PD;
  float* up    = W + OFF_UP;

  char* wsb = (char*)d_ws;
  short* Ahi  = (short*)(wsb);                 // 0..8.4MB
  short* Alo  = Ahi + 4194304;                 // 8.4..16.8MB
  short* Whi  = (short*)(wsb + 16777216);      // 16.8..23.1MB
  short* Wlo  = Whi + 3145728;                 // 23.1..29.4MB
  short* A2hi = (short*)(wsb + 50331648);      // post-scan: Qc region (dead)
  short* A2lo = A2hi + 4194304;
  short* Wdhi = (short*)(wsb + 67108864);      // post-scan: Kc region (dead)
  short* Wdlo = Wdhi + 1048576;
  short* P10h = (short*)(wsb);                 // 0..4.2MB (split ops dead)
  short* P10l = P10h + 2097152;                // 4.2..8.4MB
  short* Mrh  = (short*)(wsb + 33554432);      // 33.5..41.9MB
  short* Mrl  = Mrh + 4194304;                 // 41.9..50.3MB

  split_pre<<<dim3(2048), 256, 0, stream>>>(hs, Ahi, Alo, Wqkv, Whi, Wlo);
  gemm_bf3<1><<<dim3(24, 32), 256, 0, stream>>>(Ahi, Alo, Whi, Wlo, bqkv,
                                                nullptr, Qc, Kc, Vb,
                                                B*S, 3*HID, HID);
  k3_scores<<<dim3(16, 16, BH), 256, 0, stream>>>(Qc, Kc, partZ, pdg);
  k3_reduce<<<dim3(BH * S / 256), 256, 0, stream>>>(partZ, zi, pdg);
  k4_minv<<<dim3(S / 64, BH), 256, 0, stream>>>(Qc, Kc, zi, Mrh, Mrl,
                                                P10h, P10l);
  for (int s = 0; s < NSTEP2; ++s) {
    if (s > 0) {
      const int ng = (2 * s < 7) ? 2 * s : 7;
      k5_acc<<<dim3(ng * 2 * BH), 256, 0, stream>>>(Qc, Kc, Abuf, zi, up, s);
    }
    k5_fin<<<dim3(4, BH), 256, 0, stream>>>(Qc, Kc, Vb, pdg, zi, up,
                                            Mrh, Mrl, P10h, P10l, Abuf, s);
  }
  split_post<<<dim3(2048), 256, 0, stream>>>(Abuf, A2hi, A2lo, Wd, Wdhi, Wdlo);
  gemm_bf3<0><<<dim3(8, 32), 256, 0, stream>>>(A2hi, A2lo, Wdhi, Wdlo, bd, out,
                                               nullptr, nullptr, nullptr,
                                               B*S, HID, HID);
}